// Round 1
// baseline (24.605 us; speedup 1.0000x reference)
//
#include <hip/hip_runtime.h>
#include <math.h>

#define NB 16          // batch
#define NT 512         // time
#define NC 32          // channels
#define NW 128         // window
#define TILE_T 64
#define NTILES (NT / TILE_T)        // 8
#define NBLK (NB * NTILES)          // 128
#define NROWS (TILE_T + NW)         // 192 rows staged per block
#define WIN_MIN_F 2.0f
#define WIN_RANGE_F 62.0f           // WIN_MAX - WIN_MIN

// ws layout (floats):
// [0, NB*NT*NC)                       f_mean
// [NB*NT*NC, 2*NB*NT*NC)              f_std
// then partials: NBLK * 4 * NC
// then coeffs: 4 * NC
#define WS_FMEAN 0
#define WS_FSTD  (NB*NT*NC)
#define WS_PART  (2*NB*NT*NC)
#define WS_COEF  (WS_PART + NBLK*4*NC)

__global__ __launch_bounds__(256) void feat_main(
    const float* __restrict__ series,
    const int*   __restrict__ indices,
    const float* __restrict__ rwm,
    const float* __restrict__ rws,
    float* __restrict__ f_mean,
    float* __restrict__ f_std,
    float* __restrict__ partials)
{
    __shared__ __align__(16) float s_tile[NROWS * NC];   // 24 KB
    __shared__ float s_w1[NW * NC];                      // 16 KB
    __shared__ float s_w2[NW * NC];                      // 16 KB
    __shared__ float s_inv1[NC], s_inv2[NC];
    __shared__ float s_red[4 * 8 * NC];                  // 4 KB

    const int tid = threadIdx.x;
    const int blk = blockIdx.x;
    const int b   = blk >> 3;        // / NTILES
    const int tt  = blk & 7;
    const int t0  = tt * TILE_T;
    const int start = indices[2 * b];

    // ---- weight tables: w[w][c] = sigmoid(win[c] - (NW-1-w)) ----
    for (int i = tid; i < NW * NC; i += 256) {
        const int w = i >> 5, c = i & 31;
        const float age = (float)(NW - 1 - w);
        const float win_m = WIN_MIN_F + WIN_RANGE_F / (1.0f + expf(-rwm[c]));
        const float win_s = WIN_MIN_F + WIN_RANGE_F / (1.0f + expf(-rws[c]));
        s_w1[i] = 1.0f / (1.0f + expf(-(win_m - age)));
        s_w2[i] = 1.0f / (1.0f + expf(-(win_s - age)));
    }

    // ---- stage contiguous series slice: rows [start-NW+t0, +NROWS) ----
    const float* src = series + (size_t)(start - NW + t0) * NC;
    const float4* src4 = (const float4*)src;
    float4* dst4 = (float4*)s_tile;
    for (int j = tid; j < NROWS * NC / 4; j += 256)
        dst4[j] = src4[j];

    __syncthreads();

    if (tid < NC) {
        float s1 = 0.f, s2 = 0.f;
        for (int w = 0; w < NW; ++w) {
            s1 += s_w1[w * NC + tid];
            s2 += s_w2[w * NC + tid];
        }
        s_inv1[tid] = 1.0f / s1;
        s_inv2[tid] = 1.0f / s2;
    }
    __syncthreads();

    // ---- main compute: each thread owns channel c, 8 t-rows ----
    const int c  = tid & 31;
    const int tg = tid >> 5;          // 0..7
    const float inv1 = s_inv1[c], inv2 = s_inv2[c];

    float a1[8], a2[8], a3[8];
#pragma unroll
    for (int k = 0; k < 8; ++k) { a1[k] = 0.f; a2[k] = 0.f; a3[k] = 0.f; }

    const int tbase = tg * 8;         // rows tbase..tbase+7
#pragma unroll 4
    for (int w = 0; w < NW; ++w) {
        const float w1 = s_w1[w * NC + c];
        const float w2 = s_w2[w * NC + c];
#pragma unroll
        for (int k = 0; k < 8; ++k) {
            const float xv = s_tile[(tbase + k + w) * NC + c];
            a1[k] = fmaf(xv, w1, a1[k]);
            a2[k] = fmaf(xv, w2, a2[k]);
            a3[k] = fmaf(xv * xv, w2, a3[k]);
        }
    }

    float p0 = 0.f, p1 = 0.f, p2 = 0.f, p3 = 0.f;
#pragma unroll
    for (int k = 0; k < 8; ++k) {
        const float fm = a1[k] * inv1;
        const float m2 = a2[k] * inv2;
        float var = a3[k] * inv2 - m2 * m2;
        var = fmaxf(var, 0.0f);
        const float fs = sqrtf(var + 1e-8f);
        const int t = t0 + tbase + k;
        const size_t o = ((size_t)b * NT + t) * NC + c;
        f_mean[o] = fm;
        f_std[o]  = fs;
        p0 += fm; p1 += fm * fm; p2 += fs; p3 += fs * fs;
    }

    s_red[(0 * 8 + tg) * NC + c] = p0;
    s_red[(1 * 8 + tg) * NC + c] = p1;
    s_red[(2 * 8 + tg) * NC + c] = p2;
    s_red[(3 * 8 + tg) * NC + c] = p3;
    __syncthreads();

    if (tid < 4 * NC) {
        const int a = tid >> 5, cc = tid & 31;
        float s = 0.f;
        for (int g = 0; g < 8; ++g) s += s_red[(a * 8 + g) * NC + cc];
        partials[blk * (4 * NC) + a * NC + cc] = s;
    }
}

__global__ __launch_bounds__(128) void bn_reduce(
    const float* __restrict__ partials,
    const float* __restrict__ gm, const float* __restrict__ bm,
    const float* __restrict__ gs, const float* __restrict__ bs,
    float* __restrict__ coeffs)
{
    __shared__ float sums[4 * NC];
    const int tid = threadIdx.x;
    {
        const int a = tid >> 5, c = tid & 31;
        float s = 0.f;
        for (int blk = 0; blk < NBLK; ++blk)
            s += partials[blk * (4 * NC) + a * NC + c];
        sums[a * NC + c] = s;
    }
    __syncthreads();
    if (tid < NC) {
        const float invN = 1.0f / (float)(NB * NT);
        const float mu_m  = sums[0 * NC + tid] * invN;
        float var_m = sums[1 * NC + tid] * invN - mu_m * mu_m;
        var_m = fmaxf(var_m, 0.0f);
        const float rs_m = 1.0f / sqrtf(var_m + 1e-5f);
        const float A1 = rs_m * gm[tid];
        const float B1 = bm[tid] - mu_m * A1;
        const float mu_s  = sums[2 * NC + tid] * invN;
        float var_s = sums[3 * NC + tid] * invN - mu_s * mu_s;
        var_s = fmaxf(var_s, 0.0f);
        const float rs_s = 1.0f / sqrtf(var_s + 1e-5f);
        const float A2 = rs_s * gs[tid];
        const float B2 = bs[tid] - mu_s * A2;
        coeffs[0 * NC + tid] = A1;
        coeffs[1 * NC + tid] = B1;
        coeffs[2 * NC + tid] = A2;
        coeffs[3 * NC + tid] = B2;
    }
}

__global__ __launch_bounds__(256) void writeout(
    const float* __restrict__ x,
    const float* __restrict__ f_mean,
    const float* __restrict__ f_std,
    const float* __restrict__ coeffs,
    float* __restrict__ out)
{
    __shared__ float sc[4 * NC];
    const int tid = threadIdx.x;
    if (tid < 4 * NC) sc[tid] = coeffs[tid];
    __syncthreads();

    const int grp  = tid >> 5;   // 8 rows per block
    const int lane = tid & 31;
    const int row  = blockIdx.x * 8 + grp;       // b*NT + t
    const size_t i32 = (size_t)row * NC + lane;
    const size_t o   = (size_t)row * 96;
    out[o + lane]      = x[i32];
    out[o + 32 + lane] = fmaf(f_mean[i32], sc[lane],          sc[NC + lane]);
    out[o + 64 + lane] = fmaf(f_std[i32],  sc[2 * NC + lane], sc[3 * NC + lane]);
}

extern "C" void kernel_launch(void* const* d_in, const int* in_sizes, int n_in,
                              void* d_out, int out_size, void* d_ws, size_t ws_size,
                              hipStream_t stream) {
    const float* x      = (const float*)d_in[0];
    const float* series = (const float*)d_in[1];
    const int*   idx    = (const int*)d_in[2];
    const float* rwm    = (const float*)d_in[3];
    const float* rws    = (const float*)d_in[4];
    const float* gm     = (const float*)d_in[5];
    const float* bm     = (const float*)d_in[6];
    const float* gs     = (const float*)d_in[7];
    const float* bs     = (const float*)d_in[8];
    float* out = (float*)d_out;
    float* ws  = (float*)d_ws;

    float* f_mean   = ws + WS_FMEAN;
    float* f_std    = ws + WS_FSTD;
    float* partials = ws + WS_PART;
    float* coeffs   = ws + WS_COEF;

    feat_main<<<NBLK, 256, 0, stream>>>(series, idx, rwm, rws, f_mean, f_std, partials);
    bn_reduce<<<1, 128, 0, stream>>>(partials, gm, bm, gs, bs, coeffs);
    writeout<<<(NB * NT) / 8, 256, 0, stream>>>(x, f_mean, f_std, coeffs, out);
}